// Round 10
// baseline (762.807 us; speedup 1.0000x reference)
//
#include <hip/hip_runtime.h>
#include <hip/hip_fp16.h>

// ---------------------------------------------------------------------------
// SGCN: 2-layer GraphSAGE('gcn') + EdgeWeightNorm('right') + mean-pool + FC
// N=100k nodes, E=3.2M edges, G=64 graphs, F=64 feats.
//
// R19 -> R20 (fixing R19's two fusion regressions, per counters):
//  * Occupancy: block=bucket gave 782 blocks = 3.05/CU (32% occ) -> gather
//    latency unhidden. Now HALF-bucket per block: grid 2B=1564 (6.1/CU),
//    hn LDS 16KB, launch_bounds(256,6) -> 24 waves/CU (agg_p parity).
//  * Prefetch: restored agg_p's next-pair cnt/off prefetch (R19 paid a
//    dependent fill/off load stall at the top of every pair iteration).
//  * binB + csrsort + layout contracts byte-identical to verified build.
// Pipeline: memset, cvt, binB, csrsort, aggfc1, aggfc2, out.
// ---------------------------------------------------------------------------

#define BK   1024   // max buckets
#define NB   128    // nodes per bucket
#define CAPB 5120   // bucket capacity (mean 4096 + 16 sigma)
#define CAPP 6144   // bucket padded capacity (raw + pair-pad slack)
#define SRC17 0x1FFFFu

__device__ __forceinline__ float readlane_f(float v, int l) {
    return __int_as_float(__builtin_amdgcn_readlane(__float_as_int(v), l));
}

__device__ __forceinline__ int2 ntload_i2(const int2* p) {
    unsigned long long r = __builtin_nontemporal_load((const unsigned long long*)p);
    return make_int2((int)(unsigned)(r & 0xffffffffull), (int)(unsigned)(r >> 32));
}

__device__ __forceinline__ void ntstore_f2(float2* p, float2 v) {
    union { float2 f; unsigned long long u; } c;
    c.f = v;
    __builtin_nontemporal_store(c.u, (unsigned long long*)p);
}

// fp32 -> fp16 bulk convert (float4 -> 2x half2 per thread)
__global__ void k_cvt(const float4* __restrict__ x, uint2* __restrict__ xh, int n4) {
    int i = blockIdx.x * blockDim.x + threadIdx.x;
    if (i >= n4) return;
    float4 v = x[i];
    __half2 a = __floats2half2_rn(v.x, v.y);
    __half2 b = __floats2half2_rn(v.z, v.w);
    uint2 r;
    r.x = *(const unsigned*)&a;
    r.y = *(const unsigned*)&b;
    xh[i] = r;
}

// scan-free direct-write binning: 256 blocks x 1024 thr, chunk=E/256.
__global__ __launch_bounds__(1024) void k_binB(
        const int* __restrict__ esrc, const int* __restrict__ edst,
        const float* __restrict__ ew, int* __restrict__ cursor,
        int2* __restrict__ bsw, int E, int CH) {
    __shared__ int h[BK];                // 4 KB
    __shared__ int lcur[BK];             // 4 KB
    const int tid = threadIdx.x;

    if (tid < BK) h[tid] = 0;
    __syncthreads();
    const int e0 = blockIdx.x * CH;
    const int e1 = min(E, e0 + CH);
    for (int e = e0 + tid; e < e1; e += 1024)
        atomicAdd(&h[edst[e] >> 7], 1);
    __syncthreads();
    if (tid < BK) {
        int c = h[tid];
        lcur[tid] = c ? atomicAdd(&cursor[tid], c) : 0;
    }
    __syncthreads();
    for (int e = e0 + tid; e < e1; e += 1024) {
        int d = edst[e];
        int b = d >> 7;
        int p = atomicAdd(&lcur[b], 1);
        if (p < CAPB)
            bsw[(size_t)b * CAPB + p] =
                make_int2(((d & 127) << 18) | esrc[e], __float_as_int(ew[e]));
    }
}

// counting-sort a bucket's edges in LDS; pair-padded packed flush.
// csr entry: src(17b) | fp16-weight-sans-sign(15b) << 17.
__global__ __launch_bounds__(512) void k_csrsort(
        const int2* __restrict__ bsw, const int* __restrict__ cursor,
        unsigned* __restrict__ csr, int* __restrict__ off, int* __restrict__ fill,
        int N) {
    __shared__ unsigned se[CAPP];        // 24 KB
    __shared__ int cur[NB];
    __shared__ int pfx[NB];
    __shared__ int tot;
    const int b = blockIdx.x, tid = threadIdx.x;
    for (int i = tid; i < CAPP; i += 512) se[i] = 0u;   // pad slots stay 0
    if (tid < NB) cur[tid] = 0;
    __syncthreads();
    const int cnt = min(cursor[b], CAPB);
    const int2* __restrict__ eb = bsw + (size_t)b * CAPB;
    for (int i = tid; i < cnt; i += 512)
        atomicAdd(&cur[eb[i].x >> 18], 1);   // pass1: counts
    __syncthreads();
    int pc = 0;
    if (tid < NB) {                          // pair-padded slot size
        int c0 = cur[tid & ~1], c1 = cur[tid | 1];
        pc = (max(c0, c1) + 7) & ~7;
        pfx[tid] = pc;
    }
    __syncthreads();
    for (int o = 1; o < NB; o <<= 1) {       // Hillis-Steele over 128
        int t = 0;
        if (tid < NB && tid >= o) t = pfx[tid - o];
        __syncthreads();
        if (tid < NB) pfx[tid] += t;
        __syncthreads();
    }
    if (tid < NB) {
        int excl = pfx[tid] - pc;
        int node = b * NB + tid;
        if (node < N) { off[node] = b * CAPP + excl; fill[node] = cur[tid]; }
        cur[tid] = excl;                     // reuse as scatter cursor
        if (tid == NB - 1) tot = min(pfx[tid], CAPP);
    }
    __syncthreads();
    for (int i = tid; i < cnt; i += 512) {
        int2 e = eb[i];
        int p = atomicAdd(&cur[e.x >> 18], 1);
        unsigned h15 = (unsigned)__half_as_ushort(
                           __float2half_rn(__int_as_float(e.y))) & 0x7FFFu;
        if (p < CAPP)
            se[p] = ((unsigned)e.x & SRC17) | (h15 << 17);   // pass2: packed
    }
    __syncthreads();
    const int T = tot;
    unsigned* __restrict__ cb = csr + (size_t)b * CAPP;
    for (int i = tid; i < T; i += 512) cb[i] = se[i];
}

// ---- fused HALF-bucket agg (register accumulation, prefetched) + FC ----
// block = half bucket (64 nodes = 32 pairs), 4 waves; wave handles 8 pairs
// with the agg_p inner loop + next-pair cnt/off prefetch. hn in 16KB LDS;
// FC phase: lane = out-feat, W column in 64 VGPRs, LDS-broadcast row reads.

__global__ __launch_bounds__(256, 6) void k_aggfc1(
        const unsigned* __restrict__ xh, const int* __restrict__ off,
        const int* __restrict__ fill, const unsigned* __restrict__ csr,
        const float* __restrict__ W, const float* __restrict__ bias,
        __half* __restrict__ outh, int N) {
    __shared__ float hn[64 * 64];        // 16 KB
    const int tid  = threadIdx.x;
    const int half = blockIdx.x & 1;
    const int b    = blockIdx.x >> 1;
    const int lane = tid & 63;
    const int slot = lane >> 5;
    const int f8   = lane & 31;
    const int wv   = tid >> 6;           // 0..3
    const int node0 = b * NB + half * 64;

    // ---- agg phase: 8 pairs per wave, cnt/off prefetched ----
    int lp = wv;
    int cnt_c = 0, st_c = 0;
    {
        int nc = node0 + 2 * lp + slot;
        if (lp < 32 && nc < N) { cnt_c = fill[nc]; st_c = off[nc]; }
    }
    for (; lp < 32; lp += 4) {
        const int  node  = node0 + 2 * lp + slot;
        const bool valid = node < N;
        const int  cnt_s = cnt_c, st_s = st_c;
        {
            int nlp = lp + 4;
            int nn  = node0 + 2 * nlp + slot;
            if (nlp < 32 && nn < N) { cnt_c = fill[nn]; st_c = off[nn]; }
            else                    { cnt_c = 0; st_c = 0; }
        }
        const int cA = __builtin_amdgcn_readlane(cnt_s, 0);
        const int cB = __builtin_amdgcn_readlane(cnt_s, 32);
        const int pc = (max(cA, cB) + 7) & ~7;

        float2 acc = {0.f, 0.f};
        float  sw  = 0.f;
        const unsigned* __restrict__ pS = csr + st_s;
        for (int k = 0; k < pc; k += 8) {
            uint4 e0 = *(const uint4*)(pS + k);
            uint4 e1 = *(const uint4*)(pS + k + 4);
            unsigned ev[8] = {e0.x, e0.y, e0.z, e0.w, e1.x, e1.y, e1.z, e1.w};
            float    w[8];
            unsigned u[8];
            #pragma unroll
            for (int t = 0; t < 8; ++t) {
                unsigned e = ev[t];
                w[t] = __half2float(__ushort_as_half((unsigned short)(e >> 17)));
                u[t] = xh[((e & SRC17) << 5) | (unsigned)f8];
            }
            #pragma unroll
            for (int t = 0; t < 8; ++t) {
                float2 v = __half22float2(*(const __half2*)&u[t]);
                acc.x = fmaf(w[t], v.x, acc.x);
                acc.y = fmaf(w[t], v.y, acc.y);
                sw += w[t];
            }
        }
        if (valid) {
            float invw = (sw > 0.f) ? (1.f / sw) : 0.f;
            float invd = 1.f / ((float)cnt_s + 1.f);
            unsigned us = xh[((unsigned)node << 5) | (unsigned)f8];
            float2 xs = __half22float2(*(const __half2*)&us);
            int r = 2 * lp + slot;               // local row 0..63
            hn[r * 64 + f8 * 2    ] = (acc.x * invw + xs.x) * invd;
            hn[r * 64 + f8 * 2 + 1] = (acc.y * invw + xs.y) * invd;
        }
    }
    __syncthreads();

    // ---- FC phase: o[lane] = relu(sum_f hn[f]*W[f][lane] + b) -> fp16 ----
    float wc[64];
    #pragma unroll
    for (int f = 0; f < 64; ++f) wc[f] = W[f * 64 + lane];
    const float bb = bias[lane];
    for (int r = wv; r < 64; r += 4) {
        int node = node0 + r;
        if (node >= N) continue;
        const float4* __restrict__ row = (const float4*)&hn[r * 64];
        float o = bb;
        #pragma unroll
        for (int q = 0; q < 16; ++q) {
            float4 h4 = row[q];                   // LDS broadcast
            o = fmaf(h4.x, wc[4 * q    ], o);
            o = fmaf(h4.y, wc[4 * q + 1], o);
            o = fmaf(h4.z, wc[4 * q + 2], o);
            o = fmaf(h4.w, wc[4 * q + 3], o);
        }
        o = fmaxf(o, 0.f);
        outh[(size_t)node * 64 + lane] = __float2half_rn(o);
    }
}

// same, second layer: fused FC2 + graph mean-pool accumulate.
__global__ __launch_bounds__(256, 6) void k_aggfc2(
        const unsigned* __restrict__ xh, const int* __restrict__ off,
        const int* __restrict__ fill, const unsigned* __restrict__ csr,
        const float* __restrict__ W, const float* __restrict__ bias,
        const int* __restrict__ gid, float* __restrict__ hg,
        float* __restrict__ cntg, int N) {
    __shared__ float hn[64 * 64];        // 16 KB
    const int tid  = threadIdx.x;
    const int half = blockIdx.x & 1;
    const int b    = blockIdx.x >> 1;
    const int lane = tid & 63;
    const int slot = lane >> 5;
    const int f8   = lane & 31;
    const int wv   = tid >> 6;
    const int node0 = b * NB + half * 64;

    int lp = wv;
    int cnt_c = 0, st_c = 0;
    {
        int nc = node0 + 2 * lp + slot;
        if (lp < 32 && nc < N) { cnt_c = fill[nc]; st_c = off[nc]; }
    }
    for (; lp < 32; lp += 4) {
        const int  node  = node0 + 2 * lp + slot;
        const bool valid = node < N;
        const int  cnt_s = cnt_c, st_s = st_c;
        {
            int nlp = lp + 4;
            int nn  = node0 + 2 * nlp + slot;
            if (nlp < 32 && nn < N) { cnt_c = fill[nn]; st_c = off[nn]; }
            else                    { cnt_c = 0; st_c = 0; }
        }
        const int cA = __builtin_amdgcn_readlane(cnt_s, 0);
        const int cB = __builtin_amdgcn_readlane(cnt_s, 32);
        const int pc = (max(cA, cB) + 7) & ~7;

        float2 acc = {0.f, 0.f};
        float  sw  = 0.f;
        const unsigned* __restrict__ pS = csr + st_s;
        for (int k = 0; k < pc; k += 8) {
            uint4 e0 = *(const uint4*)(pS + k);
            uint4 e1 = *(const uint4*)(pS + k + 4);
            unsigned ev[8] = {e0.x, e0.y, e0.z, e0.w, e1.x, e1.y, e1.z, e1.w};
            float    w[8];
            unsigned u[8];
            #pragma unroll
            for (int t = 0; t < 8; ++t) {
                unsigned e = ev[t];
                w[t] = __half2float(__ushort_as_half((unsigned short)(e >> 17)));
                u[t] = xh[((e & SRC17) << 5) | (unsigned)f8];
            }
            #pragma unroll
            for (int t = 0; t < 8; ++t) {
                float2 v = __half22float2(*(const __half2*)&u[t]);
                acc.x = fmaf(w[t], v.x, acc.x);
                acc.y = fmaf(w[t], v.y, acc.y);
                sw += w[t];
            }
        }
        if (valid) {
            float invw = (sw > 0.f) ? (1.f / sw) : 0.f;
            float invd = 1.f / ((float)cnt_s + 1.f);
            unsigned us = xh[((unsigned)node << 5) | (unsigned)f8];
            float2 xs = __half22float2(*(const __half2*)&us);
            int r = 2 * lp + slot;
            hn[r * 64 + f8 * 2    ] = (acc.x * invw + xs.x) * invd;
            hn[r * 64 + f8 * 2 + 1] = (acc.y * invw + xs.y) * invd;
        }
    }
    __syncthreads();

    // ---- FC2 + mean-pool: wave wv owns rows [wv*16, wv*16+16) ----
    float wc[64];
    #pragma unroll
    for (int f = 0; f < 64; ++f) wc[f] = W[f * 64 + lane];
    const float bb = bias[lane];

    int   curg = -1;
    float acc  = 0.f;
    int   c    = 0;
    const int r0 = wv * 16, r1 = r0 + 16;
    for (int r = r0; r < r1; ++r) {
        int node = node0 + r;
        if (node >= N) break;
        const float4* __restrict__ row = (const float4*)&hn[r * 64];
        float o = bb;
        #pragma unroll
        for (int q = 0; q < 16; ++q) {
            float4 h4 = row[q];
            o = fmaf(h4.x, wc[4 * q    ], o);
            o = fmaf(h4.y, wc[4 * q + 1], o);
            o = fmaf(h4.z, wc[4 * q + 2], o);
            o = fmaf(h4.w, wc[4 * q + 3], o);
        }
        o = fmaxf(o, 0.f);
        int g = gid[node];
        if (g != curg) {
            if (c > 0) {
                atomicAdd(&hg[curg * 64 + lane], acc);
                if (lane == 0) atomicAdd(&cntg[curg], (float)c);
            }
            curg = g; acc = 0.f; c = 0;
        }
        acc += o;
        ++c;
    }
    if (c > 0) {
        atomicAdd(&hg[curg * 64 + lane], acc);
        if (lane == 0) atomicAdd(&cntg[curg], (float)c);
    }
}

// ---- fallback kernels (unchanged) ----
__global__ void k_fill_pad(const int* __restrict__ esrc, const int* __restrict__ edst,
                           const float* __restrict__ ew, int* __restrict__ fill,
                           int2* __restrict__ csr, int E, int CAP) {
    int e = blockIdx.x * blockDim.x + threadIdx.x;
    if (e < E) {
        int d = edst[e];
        int p = atomicAdd(&fill[d], 1);
        if (p < CAP)
            csr[(size_t)d * CAP + p] = make_int2(esrc[e], __float_as_int(ew[e]));
    }
}

__global__ void k_cnt(const int* __restrict__ edst, int* __restrict__ cnt, int E) {
    int e = blockIdx.x * blockDim.x + threadIdx.x;
    if (e < E) atomicAdd(&cnt[edst[e]], 1);
}

__global__ void k_off(const int* __restrict__ cnt, int* __restrict__ off,
                      int* __restrict__ fill, int* __restrict__ cursor, int N) {
    int i    = blockIdx.x * blockDim.x + threadIdx.x;
    int lane = threadIdx.x & 63;
    int c    = (i < N) ? cnt[i] : 0;
    int pref = c;
    #pragma unroll
    for (int d = 1; d < 64; d <<= 1) {
        int t = __shfl_up(pref, d);
        if (lane >= d) pref += t;
    }
    int total = __shfl(pref, 63);
    int base  = 0;
    if (lane == 63) base = atomicAdd(cursor, total);
    base = __shfl(base, 63);
    if (i < N) {
        int p = base + pref - c;
        off[i]  = p;
        fill[i] = p;
    }
}

__global__ void k_fill(const int* __restrict__ esrc, const int* __restrict__ edst,
                       const float* __restrict__ ew, int* __restrict__ fill,
                       int2* __restrict__ csr, int E) {
    int e = blockIdx.x * blockDim.x + threadIdx.x;
    if (e < E) {
        int d = edst[e];
        int p = atomicAdd(&fill[d], 1);
        csr[p] = make_int2(esrc[e], __float_as_int(ew[e]));
    }
}

// fallback gather-aggregate (int2 csr, fp16 x).
__global__ __launch_bounds__(256, 4) void k_agg_f(
        const unsigned* __restrict__ xh, const int* __restrict__ off,
        const int* __restrict__ cnt_arr, const int2* __restrict__ csr,
        float* __restrict__ agg, int N, int CAP) {
    const int lane   = threadIdx.x & 63;
    const int slot   = lane >> 5;
    const int f8     = lane & 31;
    const int wave   = (blockIdx.x * blockDim.x + threadIdx.x) >> 6;
    const int nwaves = (gridDim.x * blockDim.x) >> 6;

    int node  = wave;
    int cnt_p = 0, start_p = 0;
    if (node < N) {
        cnt_p   = cnt_arr[node];
        start_p = (CAP > 0) ? node * CAP : off[node];
        if (CAP > 0) cnt_p = min(cnt_p, CAP);
    }
    for (; node < N; node += nwaves) {
        const int cnt = cnt_p, start = start_p;
        int nn = node + nwaves;
        if (nn < N) {
            cnt_p   = cnt_arr[nn];
            start_p = (CAP > 0) ? nn * CAP : off[nn];
            if (CAP > 0) cnt_p = min(cnt_p, CAP);
        }
        int2 ee = make_int2(0, 0);
        if (lane < cnt) ee = ntload_i2(&csr[start + lane]);
        float2 acc0 = {0.f, 0.f}, acc1 = {0.f, 0.f};
        float  sw = 0.0f;
        for (int bk = 0; bk < cnt; bk += 64) {
            int   s_l = ee.x;
            float w_l = __int_as_float(ee.y);
            int2 en = make_int2(0, 0);
            int  rem = cnt - bk - 64;
            if (lane < rem) en = ntload_i2(&csr[start + bk + 64 + lane]);
            sw += w_l;
            #pragma unroll
            for (int half = 0; half < 2; ++half) {
                float    w[16];
                unsigned u[16];
                #pragma unroll
                for (int k = 0; k < 16; ++k) {
                    int idx = half * 32 + 2 * k + slot;
                    int s   = __shfl(s_l, idx);
                    w[k]    = __shfl(w_l, idx);
                    u[k]    = xh[(size_t)s * 32 + f8];
                }
                #pragma unroll
                for (int k = 0; k < 16; k += 2) {
                    float2 v0 = __half22float2(*(const __half2*)&u[k]);
                    float2 v1 = __half22float2(*(const __half2*)&u[k + 1]);
                    acc0.x = fmaf(w[k],     v0.x, acc0.x);
                    acc0.y = fmaf(w[k],     v0.y, acc0.y);
                    acc1.x = fmaf(w[k + 1], v1.x, acc1.x);
                    acc1.y = fmaf(w[k + 1], v1.y, acc1.y);
                }
            }
            ee = en;
        }
        acc0.x += acc1.x; acc0.y += acc1.y;
        acc0.x += __shfl_xor(acc0.x, 32);
        acc0.y += __shfl_xor(acc0.y, 32);
        #pragma unroll
        for (int mask = 1; mask <= 32; mask <<= 1) sw += __shfl_xor(sw, mask);
        float invw = (sw > 0.0f) ? (1.0f / sw) : 0.0f;
        float invd = 1.0f / ((float)cnt + 1.0f);
        if (lane < 32) {
            unsigned us = xh[(size_t)node * 32 + f8];
            float2 xs = __half22float2(*(const __half2*)&us);
            float2 hn;
            hn.x = (acc0.x * invw + xs.x) * invd;
            hn.y = (acc0.y * invw + xs.y) * invd;
            ntstore_f2(&((float2*)agg)[(size_t)node * 32 + f8], hn);
        }
    }
}

// k_fc: h = relu(agg @ W + b), emitted as fp16 (fallback paths).
__global__ __launch_bounds__(256) void k_fc(
        const float* __restrict__ agg, const float* __restrict__ W,
        const float* __restrict__ b, __half* __restrict__ outh, int N) {
    const int lane   = threadIdx.x & 63;
    const int wave   = (blockIdx.x * blockDim.x + threadIdx.x) >> 6;
    const int nwaves = (gridDim.x * blockDim.x) >> 6;
    float wc[64];
    #pragma unroll
    for (int f = 0; f < 64; ++f) wc[f] = W[f * 64 + lane];
    const float bias = b[lane];
    for (int node = wave; node < N; node += nwaves) {
        float hn = agg[(size_t)node * 64 + lane];
        float o0 = bias, o1 = 0.f, o2 = 0.f, o3 = 0.f;
        #pragma unroll
        for (int f = 0; f < 64; f += 4) {
            o0 = fmaf(readlane_f(hn, f),     wc[f],     o0);
            o1 = fmaf(readlane_f(hn, f + 1), wc[f + 1], o1);
            o2 = fmaf(readlane_f(hn, f + 2), wc[f + 2], o2);
            o3 = fmaf(readlane_f(hn, f + 3), wc[f + 3], o3);
        }
        float o = fmaxf((o0 + o1) + (o2 + o3), 0.0f);
        outh[(size_t)node * 64 + lane] = __float2half_rn(o);
    }
}

// fc (with relu) + mean-pool fused; gid sorted -> run-length flush (fallback).
__global__ __launch_bounds__(256) void k_fcpool(
        const float* __restrict__ agg, const float* __restrict__ W,
        const float* __restrict__ b, const int* __restrict__ gid,
        float* __restrict__ hg, float* __restrict__ cntg, int N) {
    const int lane   = threadIdx.x & 63;
    const int wave   = (blockIdx.x * blockDim.x + threadIdx.x) >> 6;
    const int nwaves = (gridDim.x * blockDim.x) >> 6;
    float wc[64];
    #pragma unroll
    for (int f = 0; f < 64; ++f) wc[f] = W[f * 64 + lane];
    const float bias = b[lane];
    const int per   = (N + nwaves - 1) / nwaves;
    const int start = wave * per;
    const int end   = min(N, start + per);
    if (start >= N) return;

    int   curg = -1;
    float acc  = 0.0f;
    int   c    = 0;
    for (int node = start; node < end; ++node) {
        float hn = agg[(size_t)node * 64 + lane];
        float o0 = bias, o1 = 0.f, o2 = 0.f, o3 = 0.f;
        #pragma unroll
        for (int f = 0; f < 64; f += 4) {
            o0 = fmaf(readlane_f(hn, f),     wc[f],     o0);
            o1 = fmaf(readlane_f(hn, f + 1), wc[f + 1], o1);
            o2 = fmaf(readlane_f(hn, f + 2), wc[f + 2], o2);
            o3 = fmaf(readlane_f(hn, f + 3), wc[f + 3], o3);
        }
        float o = fmaxf((o0 + o1) + (o2 + o3), 0.0f);
        int g = gid[node];
        if (g != curg) {
            if (c > 0) {
                atomicAdd(&hg[curg * 64 + lane], acc);
                if (lane == 0) atomicAdd(&cntg[curg], (float)c);
            }
            curg = g; acc = 0.0f; c = 0;
        }
        acc += o;
        ++c;
    }
    if (c > 0) {
        atomicAdd(&hg[curg * 64 + lane], acc);
        if (lane == 0) atomicAdd(&cntg[curg], (float)c);
    }
}

__global__ void k_out(const float* __restrict__ hg, const float* __restrict__ cntg,
                      const float* __restrict__ Wc, const float* __restrict__ bc,
                      float* __restrict__ out, int G) {
    int t = blockIdx.x * blockDim.x + threadIdx.x;
    if (t >= G * 2) return;
    int g = t >> 1, c = t & 1;
    float ct = fmaxf(cntg[g], 1.0f);
    float o  = bc[c];
    for (int f = 0; f < 64; ++f)
        o += (hg[g * 64 + f] / ct) * Wc[f * 2 + c];
    out[t] = o;
}

extern "C" void kernel_launch(void* const* d_in, const int* in_sizes, int n_in,
                              void* d_out, int out_size, void* d_ws, size_t ws_size,
                              hipStream_t stream) {
    const float* in_feat = (const float*)d_in[0];
    const float* ew      = (const float*)d_in[1];
    const float* W1      = (const float*)d_in[2];
    const float* b1      = (const float*)d_in[3];
    const float* W2      = (const float*)d_in[4];
    const float* b2      = (const float*)d_in[5];
    const float* Wc      = (const float*)d_in[6];
    const float* bc      = (const float*)d_in[7];
    const int*   esrc    = (const int*)d_in[8];
    const int*   edst    = (const int*)d_in[9];
    const int*   gid     = (const int*)d_in[10];

    const int E = in_sizes[1];
    const int N = in_sizes[10];
    const int G = out_size / 2;
    float* outp = (float*)d_out;

    auto alignup = [](size_t x) { return (x + 15) & ~(size_t)15; };
    char* base = (char*)d_ws;
    const int FC_BLK = 1024, AGG_BLK = 2048;
    const int n4 = N * 16;                             // N*64/4 float4s

    // ---- main path: binB + csrsort + fused half-bucket agg/fc ----
    const int B   = (N + NB - 1) / NB;                 // 128-node buckets
    const int CHB = (E + 255) / 256;                   // edges per binB block

    size_t zhdr  = ((size_t)G * 64 + G + BK) * 4;      // hg, cntg, cursor
    size_t o_off = alignup(zhdr);
    size_t o_fil = o_off + alignup((size_t)N * 4);
    size_t o_bsw = o_fil + alignup((size_t)N * 4);
    size_t o_csr = o_bsw + alignup((size_t)B * CAPB * 8);
    size_t o_xh  = o_csr + alignup((size_t)B * CAPP * 4);
    size_t o_th  = o_xh + alignup((size_t)N * 64 * 2);
    size_t needB = o_th + (size_t)N * 64 * 2;

    bool cap_ok = ((size_t)E / B) + 512 < CAPB && N <= (1 << 17);

    if (ws_size >= needB && B <= BK && cap_ok) {
        float*    hg     = (float*)base;
        float*    cntg   = hg + (size_t)G * 64;
        int*      cursor = (int*)(cntg + G);
        int*      off    = (int*)(base + o_off);
        int*      fill   = (int*)(base + o_fil);
        int2*     bsw    = (int2*)(base + o_bsw);
        unsigned* csr    = (unsigned*)(base + o_csr);
        unsigned* xh0    = (unsigned*)(base + o_xh);
        __half*   th1    = (__half*)(base + o_th);

        hipMemsetAsync(d_ws, 0, zhdr, stream);   // hg, cntg, cursor
        k_cvt    <<<(n4 + 255) / 256, 256, 0, stream>>>((const float4*)in_feat, (uint2*)xh0, n4);
        k_binB   <<<256, 1024, 0, stream>>>(esrc, edst, ew, cursor, bsw, E, CHB);
        k_csrsort<<<B, 512, 0, stream>>>(bsw, cursor, csr, off, fill, N);
        k_aggfc1 <<<2 * B, 256, 0, stream>>>(xh0, off, fill, csr, W1, b1, th1, N);
        k_aggfc2 <<<2 * B, 256, 0, stream>>>((const unsigned*)th1, off, fill, csr,
                                             W2, b2, gid, hg, cntg, N);
        k_out    <<<1, 128, 0, stream>>>(hg, cntg, Wc, bc, outp, G);
        return;
    }

    // ---- fallback 1: one-pass padded scatter + k_agg_f ----
    const int CAP = 96;
    size_t hdr    = ((size_t)G * 64 + G + 1 + N) * 4;
    size_t needB2 = alignup(hdr) + alignup((size_t)N * CAP * 8)
                  + alignup((size_t)N * 64 * 4) * 2
                  + alignup((size_t)N * 64 * 2) * 2;
    if (ws_size >= needB2) {
        size_t o = 0;
        float* hg     = (float*)(base + o);
        float* cntg   = hg + (size_t)G * 64;
        int*   fill   = (int*)(cntg + G) + 1;
        o += alignup(hdr);
        int2*     csr = (int2*)(base + o);    o += alignup((size_t)N * CAP * 8);
        float*    t1  = (float*)(base + o);   o += alignup((size_t)N * 64 * 4);
        float*    t2  = (float*)(base + o);   o += alignup((size_t)N * 64 * 4);
        unsigned* xh0 = (unsigned*)(base + o); o += alignup((size_t)N * 64 * 2);
        __half*   th1 = (__half*)(base + o);

        hipMemsetAsync(d_ws, 0, hdr, stream);
        k_cvt     <<<(n4 + 255) / 256, 256, 0, stream>>>((const float4*)in_feat, (uint2*)xh0, n4);
        k_fill_pad<<<(E + 255) / 256, 256, 0, stream>>>(esrc, edst, ew, fill, csr, E, CAP);
        k_agg_f <<<AGG_BLK, 256, 0, stream>>>(xh0, (const int*)nullptr, fill, csr, t1, N, CAP);
        k_fc    <<<FC_BLK, 256, 0, stream>>>(t1, W1, b1, th1, N);
        k_agg_f <<<AGG_BLK, 256, 0, stream>>>((const unsigned*)th1, (const int*)nullptr, fill, csr, t2, N, CAP);
        k_fcpool<<<FC_BLK, 256, 0, stream>>>(t2, W2, b2, gid, hg, cntg, N);
        k_out   <<<1, 128, 0, stream>>>(hg, cntg, Wc, bc, outp, G);
        return;
    }

    // ---- fallback 2: 3-pass compact CSR ----
    {
        size_t o = 0;
        float* hg     = (float*)(base + o);
        float* cntg   = hg + (size_t)G * 64;
        int*   cursor = (int*)(cntg + G);
        int*   cnt    = cursor + 1;
        o += alignup(hdr);
        int*      off  = (int*)(base + o);    o += alignup((size_t)N * 4);
        int*      fill = (int*)(base + o);    o += alignup((size_t)N * 4);
        int2*     csr  = (int2*)(base + o);   o += alignup((size_t)E * 8);
        float*    t1   = (float*)(base + o);  o += alignup((size_t)N * 64 * 4);
        float*    t2   = (float*)(base + o);  o += alignup((size_t)N * 64 * 4);
        unsigned* xh0  = (unsigned*)(base + o); o += alignup((size_t)N * 64 * 2);
        __half*   th1  = (__half*)(base + o);

        hipMemsetAsync(d_ws, 0, hdr, stream);
        k_cvt <<<(n4 + 255) / 256, 256, 0, stream>>>((const float4*)in_feat, (uint2*)xh0, n4);
        k_cnt <<<(E + 255) / 256, 256, 0, stream>>>(edst, cnt, E);
        k_off <<<(N + 255) / 256, 256, 0, stream>>>(cnt, off, fill, cursor, N);
        k_fill<<<(E + 255) / 256, 256, 0, stream>>>(esrc, edst, ew, fill, csr, E);
        k_agg_f <<<AGG_BLK, 256, 0, stream>>>(xh0, off, cnt, csr, t1, N, 0);
        k_fc    <<<FC_BLK, 256, 0, stream>>>(t1, W1, b1, th1, N);
        k_agg_f <<<AGG_BLK, 256, 0, stream>>>((const unsigned*)th1, off, cnt, csr, t2, N, 0);
        k_fcpool<<<FC_BLK, 256, 0, stream>>>(t2, W2, b2, gid, hg, cntg, N);
        k_out   <<<1, 128, 0, stream>>>(hg, cntg, Wc, bc, outp, G);
    }
}

// Round 11
// 374.468 us; speedup vs baseline: 2.0370x; 2.0370x over previous
//
#include <hip/hip_runtime.h>
#include <hip/hip_fp16.h>

// ---------------------------------------------------------------------------
// SGCN: 2-layer GraphSAGE('gcn') + EdgeWeightNorm('right') + mean-pool + FC
// N=100k nodes, E=3.2M edges, G=64 graphs, F=64 feats.
//
// R20 -> R21: REVERT to the verified R17 structure (375us; fusion lost 4
// rounds: R19 423, R18 2987, R20 762 via launch_bounds(256,6) VGPR clamp
// 64->40 -> scratch spill, FETCH 900MB / WRITE 102MB of spill traffic).
// One isolated change on top of R17:
//  * fp16 intermediates end-to-end: agg_p emits packed-fp16 rows (lane f8
//    stores one u32 = 2 halves; 128B/node coalesced); k_fc / k_fcpool read
//    fp16. Saves ~51MB streaming across 4 kernels. Layer-2 gather input was
//    already fp16, so the added rounding site is same-magnitude.
//  * binB + csrsort + all layout contracts byte-identical to R17.
// Pipeline: memset, cvt, binB, csrsort, agg, fc, agg, fcpool, out.
// ---------------------------------------------------------------------------

#define BK   1024   // max buckets
#define NB   128    // nodes per bucket
#define CAPB 5120   // bucket capacity (mean 4096 + 16 sigma)
#define CAPP 6144   // bucket padded capacity (raw + pair-pad slack)
#define SRC17 0x1FFFFu

__device__ __forceinline__ float readlane_f(float v, int l) {
    return __int_as_float(__builtin_amdgcn_readlane(__float_as_int(v), l));
}

__device__ __forceinline__ int2 ntload_i2(const int2* p) {
    unsigned long long r = __builtin_nontemporal_load((const unsigned long long*)p);
    return make_int2((int)(unsigned)(r & 0xffffffffull), (int)(unsigned)(r >> 32));
}

// fp32 -> fp16 bulk convert (float4 -> 2x half2 per thread)
__global__ void k_cvt(const float4* __restrict__ x, uint2* __restrict__ xh, int n4) {
    int i = blockIdx.x * blockDim.x + threadIdx.x;
    if (i >= n4) return;
    float4 v = x[i];
    __half2 a = __floats2half2_rn(v.x, v.y);
    __half2 b = __floats2half2_rn(v.z, v.w);
    uint2 r;
    r.x = *(const unsigned*)&a;
    r.y = *(const unsigned*)&b;
    xh[i] = r;
}

// scan-free direct-write binning: 256 blocks x 1024 thr, chunk=E/256.
__global__ __launch_bounds__(1024) void k_binB(
        const int* __restrict__ esrc, const int* __restrict__ edst,
        const float* __restrict__ ew, int* __restrict__ cursor,
        int2* __restrict__ bsw, int E, int CH) {
    __shared__ int h[BK];                // 4 KB
    __shared__ int lcur[BK];             // 4 KB
    const int tid = threadIdx.x;

    if (tid < BK) h[tid] = 0;
    __syncthreads();
    const int e0 = blockIdx.x * CH;
    const int e1 = min(E, e0 + CH);
    for (int e = e0 + tid; e < e1; e += 1024)
        atomicAdd(&h[edst[e] >> 7], 1);
    __syncthreads();
    if (tid < BK) {
        int c = h[tid];
        lcur[tid] = c ? atomicAdd(&cursor[tid], c) : 0;
    }
    __syncthreads();
    for (int e = e0 + tid; e < e1; e += 1024) {
        int d = edst[e];
        int b = d >> 7;
        int p = atomicAdd(&lcur[b], 1);
        if (p < CAPB)
            bsw[(size_t)b * CAPB + p] =
                make_int2(((d & 127) << 18) | esrc[e], __float_as_int(ew[e]));
    }
}

// counting-sort a bucket's edges in LDS; pair-padded packed flush.
// csr entry: src(17b) | fp16-weight-sans-sign(15b) << 17.
__global__ __launch_bounds__(512) void k_csrsort(
        const int2* __restrict__ bsw, const int* __restrict__ cursor,
        unsigned* __restrict__ csr, int* __restrict__ off, int* __restrict__ fill,
        int N) {
    __shared__ unsigned se[CAPP];        // 24 KB
    __shared__ int cur[NB];
    __shared__ int pfx[NB];
    __shared__ int tot;
    const int b = blockIdx.x, tid = threadIdx.x;
    for (int i = tid; i < CAPP; i += 512) se[i] = 0u;   // pad slots stay 0
    if (tid < NB) cur[tid] = 0;
    __syncthreads();
    const int cnt = min(cursor[b], CAPB);
    const int2* __restrict__ eb = bsw + (size_t)b * CAPB;
    for (int i = tid; i < cnt; i += 512)
        atomicAdd(&cur[eb[i].x >> 18], 1);   // pass1: counts
    __syncthreads();
    int pc = 0;
    if (tid < NB) {                          // pair-padded slot size
        int c0 = cur[tid & ~1], c1 = cur[tid | 1];
        pc = (max(c0, c1) + 7) & ~7;
        pfx[tid] = pc;
    }
    __syncthreads();
    for (int o = 1; o < NB; o <<= 1) {       // Hillis-Steele over 128
        int t = 0;
        if (tid < NB && tid >= o) t = pfx[tid - o];
        __syncthreads();
        if (tid < NB) pfx[tid] += t;
        __syncthreads();
    }
    if (tid < NB) {
        int excl = pfx[tid] - pc;
        int node = b * NB + tid;
        if (node < N) { off[node] = b * CAPP + excl; fill[node] = cur[tid]; }
        cur[tid] = excl;                     // reuse as scatter cursor
        if (tid == NB - 1) tot = min(pfx[tid], CAPP);
    }
    __syncthreads();
    for (int i = tid; i < cnt; i += 512) {
        int2 e = eb[i];
        int p = atomicAdd(&cur[e.x >> 18], 1);
        unsigned h15 = (unsigned)__half_as_ushort(
                           __float2half_rn(__int_as_float(e.y))) & 0x7FFFu;
        if (p < CAPP)
            se[p] = ((unsigned)e.x & SRC17) | (h15 << 17);   // pass2: packed
    }
    __syncthreads();
    const int T = tot;
    unsigned* __restrict__ cb = csr + (size_t)b * CAPP;
    for (int i = tid; i < T; i += 512) cb[i] = se[i];
}

// ---- fallback kernels ----
__global__ void k_fill_pad(const int* __restrict__ esrc, const int* __restrict__ edst,
                           const float* __restrict__ ew, int* __restrict__ fill,
                           int2* __restrict__ csr, int E, int CAP) {
    int e = blockIdx.x * blockDim.x + threadIdx.x;
    if (e < E) {
        int d = edst[e];
        int p = atomicAdd(&fill[d], 1);
        if (p < CAP)
            csr[(size_t)d * CAP + p] = make_int2(esrc[e], __float_as_int(ew[e]));
    }
}

__global__ void k_cnt(const int* __restrict__ edst, int* __restrict__ cnt, int E) {
    int e = blockIdx.x * blockDim.x + threadIdx.x;
    if (e < E) atomicAdd(&cnt[edst[e]], 1);
}

__global__ void k_off(const int* __restrict__ cnt, int* __restrict__ off,
                      int* __restrict__ fill, int* __restrict__ cursor, int N) {
    int i    = blockIdx.x * blockDim.x + threadIdx.x;
    int lane = threadIdx.x & 63;
    int c    = (i < N) ? cnt[i] : 0;
    int pref = c;
    #pragma unroll
    for (int d = 1; d < 64; d <<= 1) {
        int t = __shfl_up(pref, d);
        if (lane >= d) pref += t;
    }
    int total = __shfl(pref, 63);
    int base  = 0;
    if (lane == 63) base = atomicAdd(cursor, total);
    base = __shfl(base, 63);
    if (i < N) {
        int p = base + pref - c;
        off[i]  = p;
        fill[i] = p;
    }
}

__global__ void k_fill(const int* __restrict__ esrc, const int* __restrict__ edst,
                       const float* __restrict__ ew, int* __restrict__ fill,
                       int2* __restrict__ csr, int E) {
    int e = blockIdx.x * blockDim.x + threadIdx.x;
    if (e < E) {
        int d = edst[e];
        int p = atomicAdd(&fill[d], 1);
        csr[p] = make_int2(esrc[e], __float_as_int(ew[e]));
    }
}

// main-path gather-aggregate: wave = node PAIR. slot=lane>>5 owns node
// 2p+slot; f8=lane&31 covers the full 64-feat row as half2. Edge stream is
// packed 4 B, pair-padded to round8 with zeros -> guard-free inner loop,
// no shuffles, no cross-lane reductions. Output: packed-fp16 rows.
__global__ __launch_bounds__(256, 6) void k_agg_p(
        const unsigned* __restrict__ xh, const int* __restrict__ off,
        const int* __restrict__ cnt_arr, const unsigned* __restrict__ csr,
        unsigned* __restrict__ aggh, int N) {
    const int lane = threadIdx.x & 63;
    const int slot = lane >> 5;
    const int f8   = lane & 31;
    const int wq   = (blockIdx.x * blockDim.x + threadIdx.x) >> 6;
    const int nw   = (gridDim.x * blockDim.x) >> 6;
    const int npair = (N + 1) >> 1;

    for (int pr = wq; pr < npair; pr += nw) {
        const int  node  = 2 * pr + slot;
        const bool valid = node < N;
        const int  cnt_s = valid ? cnt_arr[node] : 0;
        const int  st_s  = valid ? off[node] : 0;
        const int  cA = __builtin_amdgcn_readlane(cnt_s, 0);
        const int  cB = __builtin_amdgcn_readlane(cnt_s, 32);
        const int  pc = (max(cA, cB) + 7) & ~7;     // == csrsort's pair pad

        float2 acc = {0.f, 0.f};
        float  sw  = 0.f;
        const unsigned* __restrict__ pS = csr + st_s;
        for (int k = 0; k < pc; k += 8) {
            // broadcast edge fetch: same addr across the slot's 32 lanes
            uint4 e0 = *(const uint4*)(pS + k);
            uint4 e1 = *(const uint4*)(pS + k + 4);
            unsigned ev[8] = {e0.x, e0.y, e0.z, e0.w, e1.x, e1.y, e1.z, e1.w};
            float    w[8];
            unsigned u[8];
            #pragma unroll
            for (int t = 0; t < 8; ++t) {
                unsigned e = ev[t];
                w[t] = __half2float(__ushort_as_half((unsigned short)(e >> 17)));
                u[t] = xh[((e & SRC17) << 5) | (unsigned)f8];
            }
            #pragma unroll
            for (int t = 0; t < 8; ++t) {
                float2 v = __half22float2(*(const __half2*)&u[t]);
                acc.x = fmaf(w[t], v.x, acc.x);
                acc.y = fmaf(w[t], v.y, acc.y);
                sw += w[t];
            }
        }
        if (valid) {
            float invw = (sw > 0.f) ? (1.f / sw) : 0.f;
            float invd = 1.f / ((float)cnt_s + 1.f);
            unsigned us = xh[((unsigned)node << 5) | (unsigned)f8];
            float2 xs = __half22float2(*(const __half2*)&us);
            float hx = (acc.x * invw + xs.x) * invd;
            float hy = (acc.y * invw + xs.y) * invd;
            __half2 hp = __floats2half2_rn(hx, hy);
            __builtin_nontemporal_store(*(const unsigned*)&hp,
                                        &aggh[(size_t)node * 32 + f8]);
        }
    }
}

// fallback gather-aggregate (int2 csr, fp16 x, packed-fp16 out).
__global__ __launch_bounds__(256, 4) void k_agg_f(
        const unsigned* __restrict__ xh, const int* __restrict__ off,
        const int* __restrict__ cnt_arr, const int2* __restrict__ csr,
        unsigned* __restrict__ aggh, int N, int CAP) {
    const int lane   = threadIdx.x & 63;
    const int slot   = lane >> 5;
    const int f8     = lane & 31;
    const int wave   = (blockIdx.x * blockDim.x + threadIdx.x) >> 6;
    const int nwaves = (gridDim.x * blockDim.x) >> 6;

    int node  = wave;
    int cnt_p = 0, start_p = 0;
    if (node < N) {
        cnt_p   = cnt_arr[node];
        start_p = (CAP > 0) ? node * CAP : off[node];
        if (CAP > 0) cnt_p = min(cnt_p, CAP);
    }
    for (; node < N; node += nwaves) {
        const int cnt = cnt_p, start = start_p;
        int nn = node + nwaves;
        if (nn < N) {
            cnt_p   = cnt_arr[nn];
            start_p = (CAP > 0) ? nn * CAP : off[nn];
            if (CAP > 0) cnt_p = min(cnt_p, CAP);
        }
        int2 ee = make_int2(0, 0);
        if (lane < cnt) ee = ntload_i2(&csr[start + lane]);
        float2 acc0 = {0.f, 0.f}, acc1 = {0.f, 0.f};
        float  sw = 0.0f;
        for (int bk = 0; bk < cnt; bk += 64) {
            int   s_l = ee.x;
            float w_l = __int_as_float(ee.y);
            int2 en = make_int2(0, 0);
            int  rem = cnt - bk - 64;
            if (lane < rem) en = ntload_i2(&csr[start + bk + 64 + lane]);
            sw += w_l;
            #pragma unroll
            for (int half = 0; half < 2; ++half) {
                float    w[16];
                unsigned u[16];
                #pragma unroll
                for (int k = 0; k < 16; ++k) {
                    int idx = half * 32 + 2 * k + slot;
                    int s   = __shfl(s_l, idx);
                    w[k]    = __shfl(w_l, idx);
                    u[k]    = xh[(size_t)s * 32 + f8];
                }
                #pragma unroll
                for (int k = 0; k < 16; k += 2) {
                    float2 v0 = __half22float2(*(const __half2*)&u[k]);
                    float2 v1 = __half22float2(*(const __half2*)&u[k + 1]);
                    acc0.x = fmaf(w[k],     v0.x, acc0.x);
                    acc0.y = fmaf(w[k],     v0.y, acc0.y);
                    acc1.x = fmaf(w[k + 1], v1.x, acc1.x);
                    acc1.y = fmaf(w[k + 1], v1.y, acc1.y);
                }
            }
            ee = en;
        }
        acc0.x += acc1.x; acc0.y += acc1.y;
        acc0.x += __shfl_xor(acc0.x, 32);
        acc0.y += __shfl_xor(acc0.y, 32);
        #pragma unroll
        for (int mask = 1; mask <= 32; mask <<= 1) sw += __shfl_xor(sw, mask);
        float invw = (sw > 0.0f) ? (1.0f / sw) : 0.0f;
        float invd = 1.0f / ((float)cnt + 1.0f);
        if (lane < 32) {
            unsigned us = xh[(size_t)node * 32 + f8];
            float2 xs = __half22float2(*(const __half2*)&us);
            float hx = (acc0.x * invw + xs.x) * invd;
            float hy = (acc0.y * invw + xs.y) * invd;
            __half2 hp = __floats2half2_rn(hx, hy);
            __builtin_nontemporal_store(*(const unsigned*)&hp,
                                        &aggh[(size_t)node * 32 + f8]);
        }
    }
}

// k_fc: h = relu(agg @ W + b), fp16 in -> fp16 out (feeds next agg gather).
// Per-lane W column in regs; readlane inner.
__global__ __launch_bounds__(256) void k_fc(
        const __half* __restrict__ agg, const float* __restrict__ W,
        const float* __restrict__ b, __half* __restrict__ outh, int N) {
    const int lane   = threadIdx.x & 63;
    const int wave   = (blockIdx.x * blockDim.x + threadIdx.x) >> 6;
    const int nwaves = (gridDim.x * blockDim.x) >> 6;
    float wc[64];
    #pragma unroll
    for (int f = 0; f < 64; ++f) wc[f] = W[f * 64 + lane];   // coalesced rows
    const float bias = b[lane];
    for (int node = wave; node < N; node += nwaves) {
        float hn = __half2float(agg[(size_t)node * 64 + lane]);
        float o0 = bias, o1 = 0.f, o2 = 0.f, o3 = 0.f;
        #pragma unroll
        for (int f = 0; f < 64; f += 4) {
            o0 = fmaf(readlane_f(hn, f),     wc[f],     o0);
            o1 = fmaf(readlane_f(hn, f + 1), wc[f + 1], o1);
            o2 = fmaf(readlane_f(hn, f + 2), wc[f + 2], o2);
            o3 = fmaf(readlane_f(hn, f + 3), wc[f + 3], o3);
        }
        float o = fmaxf((o0 + o1) + (o2 + o3), 0.0f);
        outh[(size_t)node * 64 + lane] = __float2half_rn(o);
    }
}

// fc (with relu) + mean-pool fused; gid sorted -> run-length flush. fp16 in.
__global__ __launch_bounds__(256) void k_fcpool(
        const __half* __restrict__ agg, const float* __restrict__ W,
        const float* __restrict__ b, const int* __restrict__ gid,
        float* __restrict__ hg, float* __restrict__ cntg, int N) {
    const int lane   = threadIdx.x & 63;
    const int wave   = (blockIdx.x * blockDim.x + threadIdx.x) >> 6;
    const int nwaves = (gridDim.x * blockDim.x) >> 6;
    float wc[64];
    #pragma unroll
    for (int f = 0; f < 64; ++f) wc[f] = W[f * 64 + lane];
    const float bias = b[lane];
    const int per   = (N + nwaves - 1) / nwaves;
    const int start = wave * per;
    const int end   = min(N, start + per);
    if (start >= N) return;

    int   curg = -1;
    float acc  = 0.0f;
    int   c    = 0;
    for (int node = start; node < end; ++node) {
        float hn = __half2float(agg[(size_t)node * 64 + lane]);
        float o0 = bias, o1 = 0.f, o2 = 0.f, o3 = 0.f;
        #pragma unroll
        for (int f = 0; f < 64; f += 4) {
            o0 = fmaf(readlane_f(hn, f),     wc[f],     o0);
            o1 = fmaf(readlane_f(hn, f + 1), wc[f + 1], o1);
            o2 = fmaf(readlane_f(hn, f + 2), wc[f + 2], o2);
            o3 = fmaf(readlane_f(hn, f + 3), wc[f + 3], o3);
        }
        float o = fmaxf((o0 + o1) + (o2 + o3), 0.0f);
        int g = gid[node];
        if (g != curg) {
            if (c > 0) {
                atomicAdd(&hg[curg * 64 + lane], acc);
                if (lane == 0) atomicAdd(&cntg[curg], (float)c);
            }
            curg = g; acc = 0.0f; c = 0;
        }
        acc += o;
        ++c;
    }
    if (c > 0) {
        atomicAdd(&hg[curg * 64 + lane], acc);
        if (lane == 0) atomicAdd(&cntg[curg], (float)c);
    }
}

__global__ void k_out(const float* __restrict__ hg, const float* __restrict__ cntg,
                      const float* __restrict__ Wc, const float* __restrict__ bc,
                      float* __restrict__ out, int G) {
    int t = blockIdx.x * blockDim.x + threadIdx.x;
    if (t >= G * 2) return;
    int g = t >> 1, c = t & 1;
    float ct = fmaxf(cntg[g], 1.0f);
    float o  = bc[c];
    for (int f = 0; f < 64; ++f)
        o += (hg[g * 64 + f] / ct) * Wc[f * 2 + c];
    out[t] = o;
}

extern "C" void kernel_launch(void* const* d_in, const int* in_sizes, int n_in,
                              void* d_out, int out_size, void* d_ws, size_t ws_size,
                              hipStream_t stream) {
    const float* in_feat = (const float*)d_in[0];
    const float* ew      = (const float*)d_in[1];
    const float* W1      = (const float*)d_in[2];
    const float* b1      = (const float*)d_in[3];
    const float* W2      = (const float*)d_in[4];
    const float* b2      = (const float*)d_in[5];
    const float* Wc      = (const float*)d_in[6];
    const float* bc      = (const float*)d_in[7];
    const int*   esrc    = (const int*)d_in[8];
    const int*   edst    = (const int*)d_in[9];
    const int*   gid     = (const int*)d_in[10];

    const int E = in_sizes[1];
    const int N = in_sizes[10];
    const int G = out_size / 2;
    float* outp = (float*)d_out;

    auto alignup = [](size_t x) { return (x + 15) & ~(size_t)15; };
    char* base = (char*)d_ws;
    const int FC_BLK = 1024, AGG_BLK = 2048;
    const int n4 = N * 16;                             // N*64/4 float4s

    // ---- main path: binB + csrsort + pair agg + fc (fp16 intermediates) ----
    const int B   = (N + NB - 1) / NB;                 // 128-node buckets
    const int CHB = (E + 255) / 256;                   // edges per binB block

    size_t zhdr  = ((size_t)G * 64 + G + BK) * 4;      // hg, cntg, cursor
    size_t o_off = alignup(zhdr);
    size_t o_fil = o_off + alignup((size_t)N * 4);
    size_t o_bsw = o_fil + alignup((size_t)N * 4);
    size_t o_csr = o_bsw + alignup((size_t)B * CAPB * 8);
    size_t o_t1  = o_csr + alignup((size_t)B * CAPP * 4);
    size_t o_t2  = o_t1 + alignup((size_t)N * 64 * 2);
    size_t o_xh  = o_t2 + alignup((size_t)N * 64 * 2);
    size_t o_th  = o_xh + alignup((size_t)N * 64 * 2);
    size_t needB = o_th + (size_t)N * 64 * 2;

    bool cap_ok = ((size_t)E / B) + 512 < CAPB && N <= (1 << 17);

    if (ws_size >= needB && B <= BK && cap_ok) {
        float*    hg     = (float*)base;
        float*    cntg   = hg + (size_t)G * 64;
        int*      cursor = (int*)(cntg + G);
        int*      off    = (int*)(base + o_off);
        int*      fill   = (int*)(base + o_fil);
        int2*     bsw    = (int2*)(base + o_bsw);
        unsigned* csr    = (unsigned*)(base + o_csr);
        unsigned* t1h    = (unsigned*)(base + o_t1);
        unsigned* t2h    = (unsigned*)(base + o_t2);
        unsigned* xh0    = (unsigned*)(base + o_xh);
        __half*   th1    = (__half*)(base + o_th);

        hipMemsetAsync(d_ws, 0, zhdr, stream);   // hg, cntg, cursor
        k_cvt    <<<(n4 + 255) / 256, 256, 0, stream>>>((const float4*)in_feat, (uint2*)xh0, n4);
        k_binB   <<<256, 1024, 0, stream>>>(esrc, edst, ew, cursor, bsw, E, CHB);
        k_csrsort<<<B, 512, 0, stream>>>(bsw, cursor, csr, off, fill, N);
        k_agg_p <<<AGG_BLK, 256, 0, stream>>>(xh0, off, fill, csr, t1h, N);
        k_fc    <<<FC_BLK, 256, 0, stream>>>((const __half*)t1h, W1, b1, th1, N);
        k_agg_p <<<AGG_BLK, 256, 0, stream>>>((const unsigned*)th1, off, fill, csr, t2h, N);
        k_fcpool<<<FC_BLK, 256, 0, stream>>>((const __half*)t2h, W2, b2, gid, hg, cntg, N);
        k_out   <<<1, 128, 0, stream>>>(hg, cntg, Wc, bc, outp, G);
        return;
    }

    // ---- fallback 1: one-pass padded scatter + k_agg_f ----
    const int CAP = 96;
    size_t hdr    = ((size_t)G * 64 + G + 1 + N) * 4;
    size_t needB2 = alignup(hdr) + alignup((size_t)N * CAP * 8)
                  + alignup((size_t)N * 64 * 2) * 4;
    if (ws_size >= needB2) {
        size_t o = 0;
        float* hg     = (float*)(base + o);
        float* cntg   = hg + (size_t)G * 64;
        int*   fill   = (int*)(cntg + G) + 1;
        o += alignup(hdr);
        int2*     csr = (int2*)(base + o);     o += alignup((size_t)N * CAP * 8);
        unsigned* t1h = (unsigned*)(base + o); o += alignup((size_t)N * 64 * 2);
        unsigned* t2h = (unsigned*)(base + o); o += alignup((size_t)N * 64 * 2);
        unsigned* xh0 = (unsigned*)(base + o); o += alignup((size_t)N * 64 * 2);
        __half*   th1 = (__half*)(base + o);

        hipMemsetAsync(d_ws, 0, hdr, stream);
        k_cvt     <<<(n4 + 255) / 256, 256, 0, stream>>>((const float4*)in_feat, (uint2*)xh0, n4);
        k_fill_pad<<<(E + 255) / 256, 256, 0, stream>>>(esrc, edst, ew, fill, csr, E, CAP);
        k_agg_f <<<AGG_BLK, 256, 0, stream>>>(xh0, (const int*)nullptr, fill, csr, t1h, N, CAP);
        k_fc    <<<FC_BLK, 256, 0, stream>>>((const __half*)t1h, W1, b1, th1, N);
        k_agg_f <<<AGG_BLK, 256, 0, stream>>>((const unsigned*)th1, (const int*)nullptr, fill, csr, t2h, N, CAP);
        k_fcpool<<<FC_BLK, 256, 0, stream>>>((const __half*)t2h, W2, b2, gid, hg, cntg, N);
        k_out   <<<1, 128, 0, stream>>>(hg, cntg, Wc, bc, outp, G);
        return;
    }

    // ---- fallback 2: 3-pass compact CSR ----
    {
        size_t o = 0;
        float* hg     = (float*)(base + o);
        float* cntg   = hg + (size_t)G * 64;
        int*   cursor = (int*)(cntg + G);
        int*   cnt    = cursor + 1;
        o += alignup(hdr);
        int*      off  = (int*)(base + o);     o += alignup((size_t)N * 4);
        int*      fill = (int*)(base + o);     o += alignup((size_t)N * 4);
        int2*     csr  = (int2*)(base + o);    o += alignup((size_t)E * 8);
        unsigned* t1h  = (unsigned*)(base + o); o += alignup((size_t)N * 64 * 2);
        unsigned* t2h  = (unsigned*)(base + o); o += alignup((size_t)N * 64 * 2);
        unsigned* xh0  = (unsigned*)(base + o); o += alignup((size_t)N * 64 * 2);
        __half*   th1  = (__half*)(base + o);

        hipMemsetAsync(d_ws, 0, hdr, stream);
        k_cvt <<<(n4 + 255) / 256, 256, 0, stream>>>((const float4*)in_feat, (uint2*)xh0, n4);
        k_cnt <<<(E + 255) / 256, 256, 0, stream>>>(edst, cnt, E);
        k_off <<<(N + 255) / 256, 256, 0, stream>>>(cnt, off, fill, cursor, N);
        k_fill<<<(E + 255) / 256, 256, 0, stream>>>(esrc, edst, ew, fill, csr, E);
        k_agg_f <<<AGG_BLK, 256, 0, stream>>>(xh0, off, cnt, csr, t1h, N, 0);
        k_fc    <<<FC_BLK, 256, 0, stream>>>((const __half*)t1h, W1, b1, th1, N);
        k_agg_f <<<AGG_BLK, 256, 0, stream>>>((const unsigned*)th1, off, cnt, csr, t2h, N, 0);
        k_fcpool<<<FC_BLK, 256, 0, stream>>>((const __half*)t2h, W2, b2, gid, hg, cntg, N);
        k_out   <<<1, 128, 0, stream>>>(hg, cntg, Wc, bc, outp, G);
    }
}